// Round 1
// baseline (100.724 us; speedup 1.0000x reference)
//
#include <hip/hip_runtime.h>

#define H 512
#define W 512
#define OH 506
#define OW 506
#define BC 48
#define TILE 32
#define TIN 38          // TILE + 6
#define NTX 16          // ceil(506/32)
#define NTY 16
#define NBLK (NTX*NTY*BC)
#define NPIX 12289728.0f   // 16*3*506*506

__device__ __forceinline__ float clip01(float v) {
    return fminf(fmaxf(v, 0.0f), 1.0f);
}

__global__ __launch_bounds__(256)
void ssim_tile_kernel(const float* __restrict__ pred,
                      const float* __restrict__ targ,
                      float* __restrict__ partial,     // non-null: deterministic path
                      float* __restrict__ out_atomic)  // used when partial==null
{
    __shared__ float sx[TIN][40];
    __shared__ float sy[TIN][40];
    __shared__ float sh[5][TIN][TILE];
    __shared__ float red[4];

    const int tid = threadIdx.x;
    const int tileX = blockIdx.x, tileY = blockIdx.y, bc = blockIdx.z;
    const int gx0 = tileX * TILE, gy0 = tileY * TILE;
    const long base = (long)bc * (H * W);

    // ---- stage clipped input tile (38x38) ----
    for (int idx = tid; idx < TIN * TIN; idx += 256) {
        int r = idx / TIN, c = idx - r * TIN;
        int gy = gy0 + r, gx = gx0 + c;
        float xv = 0.f, yv = 0.f;
        if (gy < H && gx < W) {
            xv = clip01(pred[base + gy * W + gx]);
            yv = clip01(targ[base + gy * W + gx]);
        }
        sx[r][c] = xv;
        sy[r][c] = yv;
    }
    __syncthreads();

    // ---- pass A: horizontal 7-sums of {x, y, xx, yy, xy} ----
    for (int idx = tid; idx < TIN * TILE; idx += 256) {
        int r = idx >> 5, j = idx & 31;   // TILE==32
        float hx = 0.f, hy = 0.f, hxx = 0.f, hyy = 0.f, hxy = 0.f;
        #pragma unroll
        for (int d = 0; d < 7; ++d) {
            float a = sx[r][j + d], b = sy[r][j + d];
            hx += a; hy += b;
            hxx = fmaf(a, a, hxx);
            hyy = fmaf(b, b, hyy);
            hxy = fmaf(a, b, hxy);
        }
        sh[0][r][j] = hx; sh[1][r][j] = hy; sh[2][r][j] = hxx;
        sh[3][r][j] = hyy; sh[4][r][j] = hxy;
    }
    __syncthreads();

    // ---- pass B: vertical sliding 7-sum, SSIM formula ----
    const int col = tid & 31;
    const int strip = tid >> 5;   // 0..7, 4 output rows each
    const int r0 = strip * 4;

    float s0 = 0.f, s1 = 0.f, s2 = 0.f, s3 = 0.f, s4 = 0.f;
    #pragma unroll
    for (int d = 0; d < 7; ++d) {
        s0 += sh[0][r0 + d][col];
        s1 += sh[1][r0 + d][col];
        s2 += sh[2][r0 + d][col];
        s3 += sh[3][r0 + d][col];
        s4 += sh[4][r0 + d][col];
    }

    const float inv  = 1.0f / 49.0f;
    const float covn = 49.0f / 48.0f;
    const float c1 = 1e-4f;    // (0.01*1.0)^2
    const float c2 = 9e-4f;    // (0.03*1.0)^2

    float acc = 0.f;
    const int ox = gx0 + col;
    #pragma unroll
    for (int rr = 0; rr < 4; ++rr) {
        int oy = gy0 + r0 + rr;
        if (oy < OH && ox < OW) {
            float ux  = s0 * inv, uy  = s1 * inv;
            float uxx = s2 * inv, uyy = s3 * inv, uxy = s4 * inv;
            float vx  = covn * (uxx - ux * ux);
            float vy  = covn * (uyy - uy * uy);
            float vxy = covn * (uxy - ux * uy);
            float num = (2.f * ux * uy + c1) * (2.f * vxy + c2);
            float den = (ux * ux + uy * uy + c1) * (vx + vy + c2);
            acc += num / den;
        }
        if (rr < 3) {
            int rin = r0 + rr;
            s0 += sh[0][rin + 7][col] - sh[0][rin][col];
            s1 += sh[1][rin + 7][col] - sh[1][rin][col];
            s2 += sh[2][rin + 7][col] - sh[2][rin][col];
            s3 += sh[3][rin + 7][col] - sh[3][rin][col];
            s4 += sh[4][rin + 7][col] - sh[4][rin][col];
        }
    }

    // ---- block reduction ----
    #pragma unroll
    for (int off = 32; off >= 1; off >>= 1)
        acc += __shfl_down(acc, off, 64);
    if ((tid & 63) == 0) red[tid >> 6] = acc;
    __syncthreads();
    if (tid == 0) {
        float s = red[0] + red[1] + red[2] + red[3];
        if (partial) {
            partial[(bc * NTY + tileY) * NTX + tileX] = s;
        } else {
            atomicAdd(out_atomic, s);
        }
    }
}

__global__ __launch_bounds__(256)
void ssim_finish_ws(const float* __restrict__ partial, float* __restrict__ out)
{
    __shared__ float red[4];
    float s = 0.f;
    for (int i = threadIdx.x; i < NBLK; i += 256) s += partial[i];
    #pragma unroll
    for (int off = 32; off >= 1; off >>= 1)
        s += __shfl_down(s, off, 64);
    if ((threadIdx.x & 63) == 0) red[threadIdx.x >> 6] = s;
    __syncthreads();
    if (threadIdx.x == 0) {
        float t = red[0] + red[1] + red[2] + red[3];
        out[0] = 1.0f - t / NPIX;
    }
}

__global__ void ssim_zero(float* out) { out[0] = 0.0f; }

__global__ void ssim_finish_atomic(float* out) { out[0] = 1.0f - out[0] / NPIX; }

extern "C" void kernel_launch(void* const* d_in, const int* in_sizes, int n_in,
                              void* d_out, int out_size, void* d_ws, size_t ws_size,
                              hipStream_t stream) {
    const float* pred = (const float*)d_in[0];
    const float* targ = (const float*)d_in[1];
    float* out = (float*)d_out;

    dim3 grid(NTX, NTY, BC);
    dim3 block(256);

    if (ws_size >= (size_t)NBLK * sizeof(float)) {
        float* part = (float*)d_ws;
        ssim_tile_kernel<<<grid, block, 0, stream>>>(pred, targ, part, nullptr);
        ssim_finish_ws<<<1, 256, 0, stream>>>(part, out);
    } else {
        ssim_zero<<<1, 1, 0, stream>>>(out);
        ssim_tile_kernel<<<grid, block, 0, stream>>>(pred, targ, nullptr, out);
        ssim_finish_atomic<<<1, 1, 0, stream>>>(out);
    }
}

// Round 2
// 93.862 us; speedup vs baseline: 1.0731x; 1.0731x over previous
//
#include <hip/hip_runtime.h>

#define W 512
#define H 512
#define OWID 506
#define OHT 506
#define BC 48            // 16 images * 3 channels
#define SW 58            // output cols per 64-wide strip (6-col halo)
#define NSTRIP 9         // ceil(506/58)
#define CH 42            // output rows per chunk (6 groups of 7)
#define NCHUNK 13        // 12*42=504, chunk 12 -> rows 504..505
#define NWAVE (BC*NSTRIP*NCHUNK)   // 5616, divisible by 4
#define NPIX 12289728.0f           // 16*3*506*506

__device__ __forceinline__ float clip01(float v) { return fminf(fmaxf(v, 0.f), 1.f); }

// sum of v over lanes l..l+6 (garbage in top lanes; masked by caller)
__device__ __forceinline__ float hsum7(float v) {
    float a1 = v + __shfl_down(v, 1, 64);          // v0+v1
    float a2 = a1 + __shfl_down(a1, 2, 64);        // v0..v3
    return a2 + __shfl_down(a1, 4, 64)             // + v4+v5
              + __shfl_down(v, 6, 64);             // + v6
}

struct Row { float x, y, xx, yy, xy; };

__device__ __forceinline__ Row hrow(const float* __restrict__ px,
                                    const float* __restrict__ py,
                                    int r, int gxc) {
    int idx = r * W + gxc;
    float x = clip01(px[idx]);
    float y = clip01(py[idx]);
    Row o;
    o.x  = hsum7(x);
    o.y  = hsum7(y);
    o.xx = hsum7(x * x);
    o.yy = hsum7(y * y);
    o.xy = hsum7(x * y);
    return o;
}

__global__ __launch_bounds__(256)
void ssim_stream(const float* __restrict__ pred, const float* __restrict__ targ,
                 float* __restrict__ partial, float* __restrict__ out_atomic)
{
    const int wid  = blockIdx.x * 4 + (threadIdx.x >> 6);
    const int lane = threadIdx.x & 63;

    const int bc    = wid / (NSTRIP * NCHUNK);
    const int rem   = wid - bc * (NSTRIP * NCHUNK);
    const int strip = rem / NCHUNK;
    const int chunk = rem - strip * NCHUNK;

    const int c0  = strip * SW;
    const int gx  = c0 + lane;
    const int gxc = min(gx, W - 1);
    const int oy0 = chunk * CH;
    const size_t base = (size_t)bc * (H * W);
    const float* px = pred + base;
    const float* py = targ + base;
    const bool colok = (lane < SW) && (gx < OWID);

    Row ring[7];
    float s0 = 0.f, s1 = 0.f, s2 = 0.f, s3 = 0.f, s4 = 0.f;
    #pragma unroll
    for (int i = 0; i < 7; ++i) {              // rows oy0..oy0+6 (<=510, no clamp)
        ring[i] = hrow(px, py, oy0 + i, gxc);
        s0 += ring[i].x;  s1 += ring[i].y;  s2 += ring[i].xx;
        s3 += ring[i].yy; s4 += ring[i].xy;
    }

    const float inv = 1.0f / 49.0f;
    const float covn = 49.0f / 48.0f;
    const float c1 = 1e-4f, c2 = 9e-4f;
    float acc = 0.f;

    #pragma unroll 1
    for (int g = 0; g < 6; ++g) {
        #pragma unroll
        for (int i = 0; i < 7; ++i) {          // t = 7g+i, ring slot = i (static)
            const int t = g * 7 + i;
            // ---- emit output row oy0+t ----
            {
                float ux = s0 * inv, uy = s1 * inv;
                float uxx = s2 * inv, uyy = s3 * inv, uxy = s4 * inv;
                float vx  = covn * (uxx - ux * ux);
                float vy  = covn * (uyy - uy * uy);
                float vxy = covn * (uxy - ux * uy);
                float num = (2.f * ux * uy + c1) * (2.f * vxy + c2);
                float den = (ux * ux + uy * uy + c1) * (vx + vy + c2);
                float v = num * __builtin_amdgcn_rcpf(den);
                bool ok = colok && (oy0 + t < OHT);
                acc += ok ? v : 0.f;
            }
            // ---- advance window: replace row oy0+t with row oy0+t+7 ----
            {
                int rn = min(oy0 + t + 7, H - 1);   // clamp; excess rows masked above
                Row nr = hrow(px, py, rn, gxc);
                s0 += nr.x  - ring[i].x;
                s1 += nr.y  - ring[i].y;
                s2 += nr.xx - ring[i].xx;
                s3 += nr.yy - ring[i].yy;
                s4 += nr.xy - ring[i].xy;
                ring[i] = nr;
            }
        }
    }

    // ---- wave reduction, one partial per wave ----
    #pragma unroll
    for (int off = 32; off >= 1; off >>= 1)
        acc += __shfl_down(acc, off, 64);
    if (lane == 0) {
        if (partial) partial[wid] = acc;
        else atomicAdd(out_atomic, acc);
    }
}

__global__ __launch_bounds__(256)
void ssim_finish(const float* __restrict__ partial, float* __restrict__ out)
{
    __shared__ float red[4];
    float s = 0.f;
    for (int i = threadIdx.x; i < NWAVE; i += 256) s += partial[i];
    #pragma unroll
    for (int off = 32; off >= 1; off >>= 1)
        s += __shfl_down(s, off, 64);
    if ((threadIdx.x & 63) == 0) red[threadIdx.x >> 6] = s;
    __syncthreads();
    if (threadIdx.x == 0) {
        float t = red[0] + red[1] + red[2] + red[3];
        out[0] = 1.0f - t / NPIX;
    }
}

__global__ void ssim_zero(float* out) { out[0] = 0.0f; }
__global__ void ssim_finish_atomic(float* out) { out[0] = 1.0f - out[0] / NPIX; }

extern "C" void kernel_launch(void* const* d_in, const int* in_sizes, int n_in,
                              void* d_out, int out_size, void* d_ws, size_t ws_size,
                              hipStream_t stream) {
    const float* pred = (const float*)d_in[0];
    const float* targ = (const float*)d_in[1];
    float* out = (float*)d_out;

    dim3 block(256);
    dim3 grid(NWAVE / 4);   // 1404 blocks, 4 waves each

    if (ws_size >= (size_t)NWAVE * sizeof(float)) {
        float* part = (float*)d_ws;
        ssim_stream<<<grid, block, 0, stream>>>(pred, targ, part, nullptr);
        ssim_finish<<<1, 256, 0, stream>>>(part, out);
    } else {
        ssim_zero<<<1, 1, 0, stream>>>(out);
        ssim_stream<<<grid, block, 0, stream>>>(pred, targ, nullptr, out);
        ssim_finish_atomic<<<1, 1, 0, stream>>>(out);
    }
}

// Round 3
// 87.951 us; speedup vs baseline: 1.1452x; 1.0672x over previous
//
#include <hip/hip_runtime.h>

#define W 512
#define H 512
#define OWID 506
#define OHT 506
#define BC 48            // 16 images * 3 channels
#define SW 58            // output cols per 64-wide strip (6-col halo)
#define NSTRIP 9         // ceil(506/58)
#define CH 21            // output rows per chunk (3 groups of 7)
#define NCHUNK 25        // 25*21=525 >= 506
#define NWAVE (BC*NSTRIP*NCHUNK)   // 10800, divisible by 4
#define NPIX 12289728.0f           // 16*3*506*506

__device__ __forceinline__ float clip01(float v) { return fminf(fmaxf(v, 0.f), 1.f); }

// sum of v over lanes l..l+6 (garbage in top lanes; masked by caller)
__device__ __forceinline__ float hsum7(float v) {
    float a1 = v + __shfl_down(v, 1, 64);          // v0+v1
    float a2 = a1 + __shfl_down(a1, 2, 64);        // v0..v3
    return a2 + __shfl_down(a1, 4, 64)             // + v4+v5
              + __shfl_down(v, 6, 64);             // + v6
}

struct Raw { float x, y; };
struct Row { float x, y, xx, yy, xy; };

__device__ __forceinline__ Raw ldraw(const float* __restrict__ px,
                                     const float* __restrict__ py,
                                     int r, int gxc) {
    Raw o;
    int idx = r * W + gxc;
    o.x = px[idx];
    o.y = py[idx];
    return o;
}

__device__ __forceinline__ Row hrow(Raw raw) {
    float x = clip01(raw.x);
    float y = clip01(raw.y);
    Row o;
    o.x  = hsum7(x);
    o.y  = hsum7(y);
    o.xx = hsum7(x * x);
    o.yy = hsum7(y * y);
    o.xy = hsum7(x * y);
    return o;
}

__global__ __launch_bounds__(256)
void ssim_stream(const float* __restrict__ pred, const float* __restrict__ targ,
                 float* __restrict__ partial, float* __restrict__ out_atomic)
{
    const int wid  = blockIdx.x * 4 + (threadIdx.x >> 6);
    const int lane = threadIdx.x & 63;

    const int bc    = wid / (NSTRIP * NCHUNK);
    const int rem   = wid - bc * (NSTRIP * NCHUNK);
    const int strip = rem / NCHUNK;
    const int chunk = rem - strip * NCHUNK;

    const int c0  = strip * SW;
    const int gx  = c0 + lane;
    const int gxc = min(gx, W - 1);
    const int oy0 = chunk * CH;
    const size_t base = (size_t)bc * (H * W);
    const float* px = pred + base;
    const float* py = targ + base;
    const bool colok = (lane < SW) && (gx < OWID);

    // ---- software pipeline: nxt holds the raw pixels for the next row ----
    Raw nxt = ldraw(px, py, oy0, gxc);

    Row ring[7];
    float s0 = 0.f, s1 = 0.f, s2 = 0.f, s3 = 0.f, s4 = 0.f;
    #pragma unroll
    for (int i = 0; i < 7; ++i) {              // rows oy0..oy0+6 (<=510+... clamped)
        Raw cur = nxt;
        nxt = ldraw(px, py, min(oy0 + i + 1, H - 1), gxc);  // prefetch next row
        ring[i] = hrow(cur);
        s0 += ring[i].x;  s1 += ring[i].y;  s2 += ring[i].xx;
        s3 += ring[i].yy; s4 += ring[i].xy;
    }

    const float inv = 1.0f / 49.0f;
    const float covn = 49.0f / 48.0f;
    const float c1 = 1e-4f, c2 = 9e-4f;
    float acc = 0.f;

    #pragma unroll 1
    for (int g = 0; g < 3; ++g) {
        #pragma unroll
        for (int i = 0; i < 7; ++i) {          // t = 7g+i, ring slot = i (static)
            const int t = g * 7 + i;
            // ---- emit output row oy0+t ----
            {
                float ux = s0 * inv, uy = s1 * inv;
                float uxx = s2 * inv, uyy = s3 * inv, uxy = s4 * inv;
                float vx  = covn * (uxx - ux * ux);
                float vy  = covn * (uyy - uy * uy);
                float vxy = covn * (uxy - ux * uy);
                float num = (2.f * ux * uy + c1) * (2.f * vxy + c2);
                float den = (ux * ux + uy * uy + c1) * (vx + vy + c2);
                float v = num * __builtin_amdgcn_rcpf(den);
                bool ok = colok && (oy0 + t < OHT);
                acc += ok ? v : 0.f;
            }
            // ---- advance: consume prefetched row oy0+t+7, prefetch oy0+t+8 ----
            {
                Raw cur = nxt;
                nxt = ldraw(px, py, min(oy0 + t + 8, H - 1), gxc);
                Row nr = hrow(cur);
                s0 += nr.x  - ring[i].x;
                s1 += nr.y  - ring[i].y;
                s2 += nr.xx - ring[i].xx;
                s3 += nr.yy - ring[i].yy;
                s4 += nr.xy - ring[i].xy;
                ring[i] = nr;
            }
        }
    }

    // ---- wave reduction, one partial per wave ----
    #pragma unroll
    for (int off = 32; off >= 1; off >>= 1)
        acc += __shfl_down(acc, off, 64);
    if (lane == 0) {
        if (partial) partial[wid] = acc;
        else atomicAdd(out_atomic, acc);
    }
}

__global__ __launch_bounds__(256)
void ssim_finish(const float* __restrict__ partial, float* __restrict__ out)
{
    __shared__ float red[4];
    float s = 0.f;
    for (int i = threadIdx.x; i < NWAVE; i += 256) s += partial[i];
    #pragma unroll
    for (int off = 32; off >= 1; off >>= 1)
        s += __shfl_down(s, off, 64);
    if ((threadIdx.x & 63) == 0) red[threadIdx.x >> 6] = s;
    __syncthreads();
    if (threadIdx.x == 0) {
        float t = red[0] + red[1] + red[2] + red[3];
        out[0] = 1.0f - t / NPIX;
    }
}

__global__ void ssim_zero(float* out) { out[0] = 0.0f; }
__global__ void ssim_finish_atomic(float* out) { out[0] = 1.0f - out[0] / NPIX; }

extern "C" void kernel_launch(void* const* d_in, const int* in_sizes, int n_in,
                              void* d_out, int out_size, void* d_ws, size_t ws_size,
                              hipStream_t stream) {
    const float* pred = (const float*)d_in[0];
    const float* targ = (const float*)d_in[1];
    float* out = (float*)d_out;

    dim3 block(256);
    dim3 grid(NWAVE / 4);   // 2700 blocks, 4 waves each

    if (ws_size >= (size_t)NWAVE * sizeof(float)) {
        float* part = (float*)d_ws;
        ssim_stream<<<grid, block, 0, stream>>>(pred, targ, part, nullptr);
        ssim_finish<<<1, 256, 0, stream>>>(part, out);
    } else {
        ssim_zero<<<1, 1, 0, stream>>>(out);
        ssim_stream<<<grid, block, 0, stream>>>(pred, targ, nullptr, out);
        ssim_finish_atomic<<<1, 1, 0, stream>>>(out);
    }
}

// Round 4
// 71.409 us; speedup vs baseline: 1.4105x; 1.2316x over previous
//
#include <hip/hip_runtime.h>

#define W 512
#define H 512
#define OWID 506
#define OHT 506
#define BC 48              // 16 images * 3 channels
#define SEGW 10            // valid outputs per 16-lane segment
#define SWOUT 40           // outputs per wave (4 segments)
#define NSTRIP 13          // ceil(506/40)
#define CH 42              // output rows per chunk (6 groups of 7)
#define NCHUNK 13          // 13*42 = 546 >= 506
#define NWAVE (BC*NSTRIP*NCHUNK)   // 8112, divisible by 4
#define NPIX 12289728.0f           // 16*3*506*506

__device__ __forceinline__ float clip01(float v) { return fminf(fmaxf(v, 0.f), 1.f); }

// DPP row_shl:N — lane p receives lane p+N within its 16-lane row; 0 if OOB.
template <int N>
__device__ __forceinline__ float dpp_shl(float v) {
    int r = __builtin_amdgcn_update_dpp(0, __float_as_int(v),
                                        0x100 + N, 0xF, 0xF, true);
    return __int_as_float(r);
}

// sum of v over lane positions p..p+6 (valid for p<=9 within each 16-lane row)
__device__ __forceinline__ float hsum7(float v) {
    float a1 = v + dpp_shl<1>(v);        // v[p]+v[p+1]
    float a2 = a1 + dpp_shl<2>(a1);      // v[p..p+3]
    return a2 + dpp_shl<4>(a1)           // + v[p+4]+v[p+5]
              + dpp_shl<6>(v);           // + v[p+6]
}

struct Raw { float x, y; };
struct Row { float x, y, xx, yy, xy; };

__device__ __forceinline__ Raw ldraw(const float* __restrict__ px,
                                     const float* __restrict__ py,
                                     int r, int gxc) {
    Raw o;
    int idx = r * W + gxc;
    o.x = px[idx];
    o.y = py[idx];
    return o;
}

__device__ __forceinline__ Row hrow(Raw raw) {
    float x = clip01(raw.x);
    float y = clip01(raw.y);
    Row o;
    o.x  = hsum7(x);
    o.y  = hsum7(y);
    o.xx = hsum7(x * x);
    o.yy = hsum7(y * y);
    o.xy = hsum7(x * y);
    return o;
}

__global__ __launch_bounds__(256)
void ssim_stream(const float* __restrict__ pred, const float* __restrict__ targ,
                 float* __restrict__ partial, float* __restrict__ out_atomic)
{
    const int wid  = blockIdx.x * 4 + (threadIdx.x >> 6);
    const int lane = threadIdx.x & 63;
    const int seg  = lane >> 4;
    const int pos  = lane & 15;

    const int bc    = wid / (NSTRIP * NCHUNK);
    const int rem   = wid - bc * (NSTRIP * NCHUNK);
    const int strip = rem / NCHUNK;
    const int chunk = rem - strip * NCHUNK;

    const int c0  = strip * SWOUT;
    const int gx  = c0 + seg * SEGW + pos;   // this lane's pixel col / output col
    const int gxc = min(gx, W - 1);
    const int oy0 = chunk * CH;
    const size_t base = (size_t)bc * (H * W);
    const float* px = pred + base;
    const float* py = targ + base;
    const bool colok = (pos <= 9) && (gx < OWID);

    // ---- software pipeline: nxt holds the raw pixels for the next row ----
    Raw nxt = ldraw(px, py, oy0, gxc);

    Row ring[7];
    float s0 = 0.f, s1 = 0.f, s2 = 0.f, s3 = 0.f, s4 = 0.f;
    #pragma unroll
    for (int i = 0; i < 7; ++i) {
        Raw cur = nxt;
        nxt = ldraw(px, py, min(oy0 + i + 1, H - 1), gxc);
        ring[i] = hrow(cur);
        s0 += ring[i].x;  s1 += ring[i].y;  s2 += ring[i].xx;
        s3 += ring[i].yy; s4 += ring[i].xy;
    }

    const float inv = 1.0f / 49.0f;
    const float covn = 49.0f / 48.0f;
    const float c1 = 1e-4f, c2 = 9e-4f;
    float acc = 0.f;

    #pragma unroll 1
    for (int g = 0; g < 6; ++g) {
        #pragma unroll
        for (int i = 0; i < 7; ++i) {          // t = 7g+i, ring slot = i (static)
            const int t = g * 7 + i;
            // ---- emit output row oy0+t ----
            {
                float ux = s0 * inv, uy = s1 * inv;
                float uxx = s2 * inv, uyy = s3 * inv, uxy = s4 * inv;
                float vx  = covn * (uxx - ux * ux);
                float vy  = covn * (uyy - uy * uy);
                float vxy = covn * (uxy - ux * uy);
                float num = (2.f * ux * uy + c1) * (2.f * vxy + c2);
                float den = (ux * ux + uy * uy + c1) * (vx + vy + c2);
                float v = num * __builtin_amdgcn_rcpf(den);
                bool ok = colok && (oy0 + t < OHT);
                acc += ok ? v : 0.f;
            }
            // ---- advance: consume prefetched row oy0+t+7, prefetch oy0+t+8 ----
            {
                Raw cur = nxt;
                nxt = ldraw(px, py, min(oy0 + t + 8, H - 1), gxc);
                Row nr = hrow(cur);
                s0 += nr.x  - ring[i].x;
                s1 += nr.y  - ring[i].y;
                s2 += nr.xx - ring[i].xx;
                s3 += nr.yy - ring[i].yy;
                s4 += nr.xy - ring[i].xy;
                ring[i] = nr;
            }
        }
    }

    // ---- wave reduction, one partial per wave ----
    #pragma unroll
    for (int off = 32; off >= 1; off >>= 1)
        acc += __shfl_down(acc, off, 64);
    if (lane == 0) {
        if (partial) partial[wid] = acc;
        else atomicAdd(out_atomic, acc);
    }
}

__global__ __launch_bounds__(256)
void ssim_finish(const float* __restrict__ partial, float* __restrict__ out)
{
    __shared__ float red[4];
    float s = 0.f;
    for (int i = threadIdx.x; i < NWAVE; i += 256) s += partial[i];
    #pragma unroll
    for (int off = 32; off >= 1; off >>= 1)
        s += __shfl_down(s, off, 64);
    if ((threadIdx.x & 63) == 0) red[threadIdx.x >> 6] = s;
    __syncthreads();
    if (threadIdx.x == 0) {
        float t = red[0] + red[1] + red[2] + red[3];
        out[0] = 1.0f - t / NPIX;
    }
}

__global__ void ssim_zero(float* out) { out[0] = 0.0f; }
__global__ void ssim_finish_atomic(float* out) { out[0] = 1.0f - out[0] / NPIX; }

extern "C" void kernel_launch(void* const* d_in, const int* in_sizes, int n_in,
                              void* d_out, int out_size, void* d_ws, size_t ws_size,
                              hipStream_t stream) {
    const float* pred = (const float*)d_in[0];
    const float* targ = (const float*)d_in[1];
    float* out = (float*)d_out;

    dim3 block(256);
    dim3 grid(NWAVE / 4);   // 2028 blocks, 4 waves each

    if (ws_size >= (size_t)NWAVE * sizeof(float)) {
        float* part = (float*)d_ws;
        ssim_stream<<<grid, block, 0, stream>>>(pred, targ, part, nullptr);
        ssim_finish<<<1, 256, 0, stream>>>(part, out);
    } else {
        ssim_zero<<<1, 1, 0, stream>>>(out);
        ssim_stream<<<grid, block, 0, stream>>>(pred, targ, nullptr, out);
        ssim_finish_atomic<<<1, 1, 0, stream>>>(out);
    }
}

// Round 6
// 58.687 us; speedup vs baseline: 1.7163x; 1.2168x over previous
//
#include <hip/hip_runtime.h>

#define W 512
#define H 512
#define OWID 506
#define OHT 506
#define BC 48              // 16 images * 3 channels
#define SEGW 10            // valid outputs per 16-lane segment
#define SWOUT 40           // outputs per wave (4 segments)
#define NSTRIP 13          // ceil(506/40)
#define CH 42              // output rows per chunk (6 groups of 7)
#define NCHUNK 13          // 13*42 = 546 >= 506
#define NWAVE (BC*NSTRIP*NCHUNK)   // 8112, divisible by 4
#define NPIX 12289728.0f           // 16*3*506*506

__device__ __forceinline__ float clip01(float v) { return fminf(fmaxf(v, 0.f), 1.f); }

// DPP row_shl:N — lane p receives lane p+N within its 16-lane row; 0 if OOB.
template <int N>
__device__ __forceinline__ float dpp_shl(float v) {
    int r = __builtin_amdgcn_update_dpp(0, __float_as_int(v),
                                        0x100 + N, 0xF, 0xF, true);
    return __int_as_float(r);
}

// sum of v over lane positions p..p+6 (valid for p<=9 within each 16-lane row)
__device__ __forceinline__ float hsum7(float v) {
    float a1 = v + dpp_shl<1>(v);        // v[p]+v[p+1]
    float a2 = a1 + dpp_shl<2>(a1);      // v[p..p+3]
    return a2 + dpp_shl<4>(a1)           // + v[p+4]+v[p+5]
              + dpp_shl<6>(v);           // + v[p+6]
}

struct Row { float x, y, xx, yy, xy; };

__device__ __forceinline__ Row hrow(float rx, float ry) {
    float x = clip01(rx);
    float y = clip01(ry);
    Row o;
    o.x  = hsum7(x);
    o.y  = hsum7(y);
    o.xx = hsum7(x * x);
    o.yy = hsum7(y * y);
    o.xy = hsum7(x * y);
    return o;
}

__global__ __launch_bounds__(256)
void ssim_stream(const float* __restrict__ pred, const float* __restrict__ targ,
                 float* __restrict__ partial, float* __restrict__ out_atomic)
{
    // wave-uniform id forced into SGPRs -> scalar addressing / scalar loop math
    const int wid  = __builtin_amdgcn_readfirstlane(blockIdx.x * 4 + (threadIdx.x >> 6));
    const int lane = threadIdx.x & 63;
    const int seg  = lane >> 4;
    const int pos  = lane & 15;

    const int bc    = wid / (NSTRIP * NCHUNK);
    const int rem   = wid - bc * (NSTRIP * NCHUNK);
    const int strip = rem / NCHUNK;
    const int chunk = rem - strip * NCHUNK;

    const int gx  = strip * SWOUT + seg * SEGW + pos;  // pixel col / output col
    const int gxc = min(gx, W - 1);
    const int oy0 = chunk * CH;
    const bool colok = (pos <= 9) && (gx < OWID);

    const size_t base = (size_t)bc * (H * W) + (size_t)oy0 * W;
    const float* __restrict__ px = pred + base;   // scalar base, row oy0
    const float* __restrict__ py = targ + base;

    // ---- init: rows 0..6 (relative); oy0<=504 so rows <=510, in-bounds ----
    Row ring[7];
    float s0 = 0.f, s1 = 0.f, s2 = 0.f, s3 = 0.f, s4 = 0.f;
    #pragma unroll
    for (int i = 0; i < 7; ++i) {
        ring[i] = hrow(px[i * W + gxc], py[i * W + gxc]);
        s0 += ring[i].x;  s1 += ring[i].y;  s2 += ring[i].xx;
        s3 += ring[i].yy; s4 += ring[i].xy;
    }

    // ---- software-pipeline prefetch of row 7 (oy0+7 <= 511, in-bounds) ----
    float nx = px[7 * W + gxc];
    float ny = py[7 * W + gxc];
    // scalar row pointers for the NEXT prefetch, clamped to last valid row
    const int r8 = min(oy0 + 8, H - 1) - oy0;     // relative, clamped (fixes R5 OOB)
    const float* fx = px + r8 * W;
    const float* fy = py + r8 * W;
    int rabs = oy0 + 8;             // unclamped absolute row fx/fy "want" to point at

    // sum-domain SSIM constants (num/den scaled by 49^4)
    const float c1p   = 0.2401f;        // C1 * 49^2
    const float c2p   = 2.1609f;        // C2 * 49^2
    const float covn  = 49.0f / 48.0f;
    const float covn2 = 49.0f / 24.0f;  // 2*covn
    float acc = 0.f;

    #pragma unroll 1
    for (int g = 0; g < 6; ++g) {
        if (oy0 + 7 * g >= OHT) break;     // scalar early-exit (last chunk)
        #pragma unroll
        for (int i = 0; i < 7; ++i) {      // t = 7g+i, ring slot = i (static)
            const int t = g * 7 + i;
            // ---- emit output row oy0+t (sum-domain formula) ----
            {
                float t01 = s0 * s1;
                float qs  = fmaf(s0, s0, s1 * s1);
                float w4  = fmaf(49.f, s4, -t01);
                float num1 = fmaf(2.f, t01, c1p);
                float num2 = fmaf(covn2, w4, c2p);
                float s23 = s2 + s3;
                float w23 = fmaf(49.f, s23, -qs);
                float den1 = qs + c1p;
                float den2 = fmaf(covn, w23, c2p);
                float num = num1 * num2;
                float den = den1 * den2;
                float v = num * __builtin_amdgcn_rcpf(den);
                bool ok = colok && (oy0 + t < OHT);   // row check is scalar
                acc += ok ? v : 0.f;
            }
            // ---- advance: consume prefetched row t+7, prefetch row t+8 ----
            {
                Row nr = hrow(nx, ny);
                nx = fx[gxc];
                ny = fy[gxc];
                if (rabs < H - 1) { fx += W; fy += W; }  // scalar clamp guard
                ++rabs;
                s0 += nr.x  - ring[i].x;
                s1 += nr.y  - ring[i].y;
                s2 += nr.xx - ring[i].xx;
                s3 += nr.yy - ring[i].yy;
                s4 += nr.xy - ring[i].xy;
                ring[i] = nr;
            }
        }
    }

    // ---- wave reduction, one partial per wave ----
    #pragma unroll
    for (int off = 32; off >= 1; off >>= 1)
        acc += __shfl_down(acc, off, 64);
    if (lane == 0) {
        if (partial) partial[wid] = acc;
        else atomicAdd(out_atomic, acc);
    }
}

__global__ __launch_bounds__(256)
void ssim_finish(const float* __restrict__ partial, float* __restrict__ out)
{
    __shared__ float red[4];
    float s = 0.f;
    for (int i = threadIdx.x; i < NWAVE; i += 256) s += partial[i];
    #pragma unroll
    for (int off = 32; off >= 1; off >>= 1)
        s += __shfl_down(s, off, 64);
    if ((threadIdx.x & 63) == 0) red[threadIdx.x >> 6] = s;
    __syncthreads();
    if (threadIdx.x == 0) {
        float t = red[0] + red[1] + red[2] + red[3];
        out[0] = 1.0f - t / NPIX;
    }
}

__global__ void ssim_zero(float* out) { out[0] = 0.0f; }
__global__ void ssim_finish_atomic(float* out) { out[0] = 1.0f - out[0] / NPIX; }

extern "C" void kernel_launch(void* const* d_in, const int* in_sizes, int n_in,
                              void* d_out, int out_size, void* d_ws, size_t ws_size,
                              hipStream_t stream) {
    const float* pred = (const float*)d_in[0];
    const float* targ = (const float*)d_in[1];
    float* out = (float*)d_out;

    dim3 block(256);
    dim3 grid(NWAVE / 4);   // 2028 blocks, 4 waves each

    if (ws_size >= (size_t)NWAVE * sizeof(float)) {
        float* part = (float*)d_ws;
        ssim_stream<<<grid, block, 0, stream>>>(pred, targ, part, nullptr);
        ssim_finish<<<1, 256, 0, stream>>>(part, out);
    } else {
        ssim_zero<<<1, 1, 0, stream>>>(out);
        ssim_stream<<<grid, block, 0, stream>>>(pred, targ, nullptr, out);
        ssim_finish_atomic<<<1, 1, 0, stream>>>(out);
    }
}